// Round 16
// baseline (197.523 us; speedup 1.0000x reference)
//
#include <hip/hip_runtime.h>
#include <hip/hip_bf16.h>

typedef __hip_bfloat16 bf16_t;
typedef __attribute__((ext_vector_type(8))) __bf16 bf16x8;
typedef __attribute__((ext_vector_type(4))) float f32x4;
typedef __attribute__((ext_vector_type(4))) unsigned short ushort4v;
typedef __attribute__((ext_vector_type(4))) short short4v;

#define NUM_B 2
#define NUM_H 16
#define SEQ   2048
#define EMB   1024
#define LOG2E 1.44269504088896340736f
#define LN10K 13.287712379549449f   // log2(10000)

// ---------------- prep: cast x, transpose+cast weights, fill RoPE table ----------------
__global__ __launch_bounds__(256) void prep_kernel(
    const float* __restrict__ x, const float* __restrict__ wq,
    const float* __restrict__ wo, bf16_t* __restrict__ xb,
    bf16_t* __restrict__ wqT, bf16_t* __restrict__ woT,
    float2* __restrict__ rope) {
  __shared__ float tile[32][33];
  int bid = blockIdx.x, tid = threadIdx.x;
  if (bid < 4096) {                 // cast x (4M elems)
    int i = (bid * 256 + tid) * 4;
    f32x4 v = *(const f32x4*)&x[i];
    ushort4v p;
#pragma unroll
    for (int j = 0; j < 4; ++j)
      p[j] = __builtin_bit_cast(unsigned short, __float2bfloat16(v[j]));
    *(ushort4v*)&xb[i] = p;
    return;
  }
  if (bid >= 8192) {                // RoPE table: rope[s*32+i] = {cos,sin}(s*inv_i)
    int idx = (bid - 8192) * 256 + tid;
    int s = idx >> 5, i = idx & 31;
    float inv = exp2f(-(float)i * (LN10K / 32.0f));
    float sn, cs;
    sincosf((float)s * inv, &sn, &cs);
    rope[idx] = make_float2(cs, sn);
    return;
  }
  const float* src;
  bf16_t* dst;
  int R, C, c0, r0;
  if (bid < 4096 + 3072) {          // w_qkv [1024,3072] -> wqT [3072,1024]
    int b = bid - 4096;
    src = wq; dst = wqT; R = 1024; C = 3072;
    c0 = (b % 96) * 32; r0 = (b / 96) * 32;
  } else {                          // w_o [1024,1024] -> woT
    int b = bid - 7168;
    src = wo; dst = woT; R = 1024; C = 1024;
    c0 = (b % 32) * 32; r0 = (b / 32) * 32;
  }
  int tx = tid & 31, ty = tid >> 5;
#pragma unroll
  for (int i = 0; i < 4; ++i)
    tile[ty + i * 8][tx] = src[(size_t)(r0 + ty + i * 8) * C + c0 + tx];
  __syncthreads();
#pragma unroll
  for (int i = 0; i < 4; ++i)
    dst[(size_t)(c0 + ty + i * 8) * R + r0 + tx] = __float2bfloat16(tile[tx][ty + i * 8]);
}

// ---------------- GEMM: C = A[M,K]bf16 * Bt[N,K]bf16^T + bias(f32) ----------------
// Tile (32*MT) x 128, BK=32, SINGLE-buffer LDS + 2 barriers/iter (r13 proven;
// dbuf regressed: 2x LDS halved occupancy, killed implicit wave overlap).
// XOR swizzle g^((row>>1)&3) keeps b128 frag reads 2-way (free).
// A-tile = 128*MT chunks -> CH=MT/2 per thread; B-tile 128 rows -> CH=2.
template <int CH>
__device__ __forceinline__ void stage_tile(const bf16_t* __restrict__ G,
                                           int row0, int col0, int ld,
                                           bf16_t* Ls, int tid) {
#pragma unroll
  for (int r = 0; r < CH; ++r) {
    int c = tid + r * 256;
    int row = c >> 2, g = c & 3;
    const char* gp = (const char*)(G + (size_t)(row0 + row) * ld + col0) +
                     ((g ^ ((row >> 1) & 3)) * 16);
    char* lp = (char*)Ls + c * 16;
    __builtin_amdgcn_global_load_lds((const __attribute__((address_space(1))) void*)gp,
                                     (__attribute__((address_space(3))) void*)lp, 16, 0, 0);
  }
}

template <int MODE, int MT>
__global__ __launch_bounds__(256) void gemm_bf16_kernel(
    const bf16_t* __restrict__ A, const bf16_t* __restrict__ Bt,
    const float* __restrict__ bias, const float2* __restrict__ rope,
    bf16_t* __restrict__ out0, bf16_t* __restrict__ out1,
    bf16_t* __restrict__ out2, float* __restrict__ outf, int Ndim, int Kdim) {
  __shared__ __align__(16) bf16_t As[MT * 32 * 32];
  __shared__ __align__(16) bf16_t Bs[128 * 32];
  int tid = threadIdx.x;
  int wave = tid >> 6, lane = tid & 63;
  int lr = lane & 15, lq = lane >> 4;
  int m0 = blockIdx.x * (32 * MT), n0 = blockIdx.y * 128;
  int wm = (wave >> 1) * (MT * 16), wn = (wave & 1) * 64;
  int key = (lr >> 1) & 3;            // frag-read swizzle key
  int goff = ((lq ^ key) * 8);        // swizzled 16B-group elem offset
  f32x4 acc[MT][4];
#pragma unroll
  for (int i = 0; i < MT; ++i)
#pragma unroll
    for (int j = 0; j < 4; ++j) acc[i][j] = (f32x4){0.f, 0.f, 0.f, 0.f};

  for (int k0 = 0; k0 < Kdim; k0 += 32) {
    __syncthreads();
    stage_tile<MT / 2>(A, m0, k0, Kdim, As, tid);
    stage_tile<2>(Bt, n0, k0, Kdim, Bs, tid);
    __syncthreads();
    bf16x8 af[MT], bfr[4];
#pragma unroll
    for (int mt = 0; mt < MT; ++mt)
      af[mt] = *(const bf16x8*)&As[(wm + mt * 16 + lr) * 32 + goff];
#pragma unroll
    for (int nt = 0; nt < 4; ++nt)
      bfr[nt] = *(const bf16x8*)&Bs[(wn + nt * 16 + lr) * 32 + goff];
#pragma unroll
    for (int mt = 0; mt < MT; ++mt)
#pragma unroll
      for (int nt = 0; nt < 4; ++nt)
        acc[mt][nt] = __builtin_amdgcn_mfma_f32_16x16x32_bf16(af[mt], bfr[nt], acc[mt][nt], 0, 0, 0);
  }

  if (MODE == 0) {
    // pair (nt=pr, nt=pr+2): same lane holds d=pr*16+lr (<32) and d+32
#pragma unroll
    for (int pr = 0; pr < 2; ++pr) {
      int na = n0 + wn + pr * 16 + lr;
      int nb = na + 32;
      int sec = na >> 10;               // 0=q 1=k 2=v (uniform across pair)
      int h = (na >> 6) & (NUM_H - 1);
      int da = na & 63;                 // < 32
      float bva = bias[na], bvb = bias[nb];
      if (sec == 2) {
#pragma unroll
        for (int mt = 0; mt < MT; ++mt) {
          int mbase = m0 + wm + mt * 16 + lq * 4;
          int b = mbase >> 11;
          int s = mbase & (SEQ - 1);
          int bh = b * NUM_H + h;
          ushort4v pa, pb;
#pragma unroll
          for (int r = 0; r < 4; ++r) {
            pa[r] = __builtin_bit_cast(unsigned short, __float2bfloat16(acc[mt][pr][r] + bva));
            pb[r] = __builtin_bit_cast(unsigned short, __float2bfloat16(acc[mt][pr + 2][r] + bvb));
          }
          *(ushort4v*)&out2[((size_t)bh * 64 + da) * SEQ + s] = pa;
          *(ushort4v*)&out2[((size_t)bh * 64 + da + 32) * SEQ + s] = pb;
        }
      } else {
        bf16_t* dst = (sec == 0) ? out0 : out1;
        float scale = (sec == 0) ? 0.125f : 1.0f;
#pragma unroll
        for (int mt = 0; mt < MT; ++mt) {
          int mbase = m0 + wm + mt * 16 + lq * 4;
          int b = mbase >> 11;
          int s0 = mbase & (SEQ - 1);
          int bh = b * NUM_H + h;
#pragma unroll
          for (int r = 0; r < 4; ++r) {
            float2 rs = rope[(s0 + r) * 32 + da];   // {cos, sin}
            float va = acc[mt][pr][r] + bva;
            float vb = acc[mt][pr + 2][r] + bvb;
            float oa = (va * rs.x - vb * rs.y) * scale;
            float ob = (vb * rs.x + va * rs.y) * scale;
            size_t rowb = ((size_t)bh * SEQ + (s0 + r)) * 64;
            dst[rowb + da] = __float2bfloat16(oa);
            dst[rowb + da + 32] = __float2bfloat16(ob);
          }
        }
      }
    }
  } else {
#pragma unroll
    for (int nt = 0; nt < 4; ++nt) {
      int n = n0 + wn + nt * 16 + lr;
      float bv = bias[n];
#pragma unroll
      for (int mt = 0; mt < MT; ++mt)
#pragma unroll
        for (int r = 0; r < 4; ++r) {
          int m = m0 + wm + mt * 16 + lq * 4 + r;
          outf[(size_t)m * Ndim + n] = acc[mt][nt][r] + bv;
        }
    }
  }
}

// ---------------- flash attention v8: register-P (no Psh), K=16 PV MFMA ----------------
__device__ __forceinline__ void stage_sw(const char* __restrict__ gbase,
                                         size_t rowStride, bf16_t* lds, int tid) {
  // 64 rows x 128B, swizzled: LDS slot (row,g) <- global (row, g^(row&7))
#pragma unroll
  for (int r = 0; r < 2; ++r) {
    int c = tid + r * 256;
    int row = c >> 3, g = c & 7;
    const char* gp = gbase + (size_t)row * rowStride + ((g ^ (row & 7)) * 16);
    char* lp = (char*)lds + c * 16;
    __builtin_amdgcn_global_load_lds((const __attribute__((address_space(1))) void*)gp,
                                     (__attribute__((address_space(3))) void*)lp, 16, 0, 0);
  }
}

__global__ __launch_bounds__(256) void flash_attn_kernel(
    const bf16_t* __restrict__ Q, const bf16_t* __restrict__ K,
    const bf16_t* __restrict__ Vt, bf16_t* __restrict__ O) {
  __shared__ __align__(16) bf16_t Ks[2][64 * 64];
  __shared__ __align__(16) bf16_t Vs[2][64 * 64];
  int tid = threadIdx.x;
  int wv = tid >> 6, lane = tid & 63;
  int lr = lane & 15, lq = lane >> 4;
  int bx = blockIdx.x;
  int bh = bx & 31;
  int tile = 31 - (bx >> 5);        // longest blocks dispatched first
  int qw0 = tile * 64 + wv * 16;
  const bf16_t* Qb = Q + (size_t)bh * SEQ * 64;
  const bf16_t* Kb = K + (size_t)bh * SEQ * 64;
  const bf16_t* Vb = Vt + (size_t)bh * 64 * SEQ;
  int sw = lr & 7;                  // row-swizzle key for frag reads
  int g0 = (lq ^ sw) * 8;           // elem offset of 16B group lq, row-swizzled
  int g1 = g0 ^ 32;                 // group lq+4

  bf16x8 aq0 = *(const bf16x8*)&Qb[(size_t)(qw0 + lr) * 64 + lq * 8];
  bf16x8 aq1 = *(const bf16x8*)&Qb[(size_t)(qw0 + lr) * 64 + 32 + lq * 8];

  f32x4 Oacc[4];
#pragma unroll
  for (int dt = 0; dt < 4; ++dt) Oacc[dt] = (f32x4){0.f, 0.f, 0.f, 0.f};
  float lrow = 0.f;

  int nch = tile + 1;
  stage_sw((const char*)Kb, 128, Ks[0], tid);
  stage_sw((const char*)Vb, SEQ * 2, Vs[0], tid);

  for (int ch = 0; ch < nch; ++ch) {
    int cur = ch & 1;
    bool diag = (ch == tile);
    __syncthreads();               // buf[cur] staged (vmcnt), buf[1-cur] reads done (lgkm)
    if (ch + 1 < nch) {            // prefetch next chunk; compute below covers latency
      int kvn = (ch + 1) * 64;
      stage_sw((const char*)(Kb + (size_t)kvn * 64), 128, Ks[cur ^ 1], tid);
      stage_sw((const char*)Vb + (size_t)kvn * 2, SEQ * 2, Vs[cur ^ 1], tid);
    }

    // S^T = K*Q^T, p = exp(s) packed in-register (B-frag of K=16 PV MFMA),
    // then O^T += Vt*P, all per kv-sub (independent chains)
#pragma unroll
    for (int sub = 0; sub < 4; ++sub) {
      if (!diag || sub <= wv) {    // wave-uniform
        int rk = (sub * 16 + lr) * 64;
        bf16x8 k0 = *(const bf16x8*)&Ks[cur][rk + g0];
        bf16x8 k1 = *(const bf16x8*)&Ks[cur][rk + g1];
        f32x4 t = (f32x4){0.f, 0.f, 0.f, 0.f};
        t = __builtin_amdgcn_mfma_f32_16x16x32_bf16(k0, aq0, t, 0, 0, 0);
        t = __builtin_amdgcn_mfma_f32_16x16x32_bf16(k1, aq1, t, 0, 0, 0);
        if (diag && sub == wv) {   // causal: kv_local > q_local
#pragma unroll
          for (int r = 0; r < 4; ++r)
            if (lq * 4 + r > lr) t[r] = -1e30f;
        }
        short4v pp;
#pragma unroll
        for (int r = 0; r < 4; ++r) {
          float p = exp2f(t[r] * LOG2E);
          lrow += p;
          pp[r] = __builtin_bit_cast(short, __float2bfloat16(p));
        }
        // PV: A = Vt[d-sub][kv 16 of this sub] (b64, swizzled), B = pp (regs)
#pragma unroll
        for (int dt = 0; dt < 4; ++dt) {
          int row = dt * 16 + lr;
          int grp = (sub * 2 + (lq >> 1)) ^ sw;         // 16B group, swizzled
          short4v av = *(const short4v*)&Vs[cur][row * 64 + grp * 8 + (lq & 1) * 4];
          Oacc[dt] = __builtin_amdgcn_mfma_f32_16x16x16bf16_1k(av, pp, Oacc[dt], 0, 0, 0);
        }
      }
    }
  }

  lrow += __shfl_xor(lrow, 16, 64);
  lrow += __shfl_xor(lrow, 32, 64);

  int b = bh >> 4, h = bh & (NUM_H - 1);
  int q = qw0 + lr;
  size_t base = (((size_t)b * SEQ + q) * NUM_H + h) * 64;
  float rinv = 1.0f / lrow;
#pragma unroll
  for (int dt = 0; dt < 4; ++dt) {
    ushort4v ok;
#pragma unroll
    for (int r = 0; r < 4; ++r)
      ok[r] = __builtin_bit_cast(unsigned short, __float2bfloat16(Oacc[dt][r] * rinv));
    *(ushort4v*)&O[base + dt * 16 + lq * 4] = ok;
  }
}

extern "C" void kernel_launch(void* const* d_in, const int* in_sizes, int n_in,
                              void* d_out, int out_size, void* d_ws, size_t ws_size,
                              hipStream_t stream) {
  const float* x      = (const float*)d_in[0];
  const float* w_qkv  = (const float*)d_in[1];
  const float* b_qkv  = (const float*)d_in[2];
  const float* w_o    = (const float*)d_in[3];
  const float* b_o    = (const float*)d_in[4];
  float* out = (float*)d_out;

  bf16_t* ws    = (bf16_t*)d_ws;
  bf16_t* xb    = ws;                       // [4096,1024]   8MB
  bf16_t* wqkvT = xb + 4 * 1024 * 1024;     // [3072,1024]   6MB
  bf16_t* woT   = wqkvT + 3072 * 1024;      // [1024,1024]   2MB
  bf16_t* Qb    = woT + 1024 * 1024;        // [32,2048,64]  8MB
  bf16_t* Kb    = Qb + 4 * 1024 * 1024;     // [32,2048,64]  8MB
  bf16_t* Vt    = Kb + 4 * 1024 * 1024;     // [32,64,2048]  8MB
  bf16_t* attn  = Vt + 4 * 1024 * 1024;     // [4096,1024]   8MB
  float2* rope  = (float2*)(attn + 4 * 1024 * 1024);  // 2048*32 float2 0.5MB

  prep_kernel<<<8448, 256, 0, stream>>>(x, w_qkv, w_o, xb, wqkvT, woT, rope);
  gemm_bf16_kernel<0, 4><<<dim3(32, 24), 256, 0, stream>>>(
      xb, wqkvT, b_qkv, rope, Qb, Kb, Vt, nullptr, 3072, 1024);
  flash_attn_kernel<<<1024, 256, 0, stream>>>(Qb, Kb, Vt, attn);
  gemm_bf16_kernel<1, 2><<<dim3(64, 8), 256, 0, stream>>>(
      attn, woT, b_o, nullptr, nullptr, nullptr, nullptr, out, 1024, 1024);
}

// Round 17
// 182.086 us; speedup vs baseline: 1.0848x; 1.0848x over previous
//
#include <hip/hip_runtime.h>
#include <hip/hip_bf16.h>

typedef __hip_bfloat16 bf16_t;
typedef __attribute__((ext_vector_type(8))) __bf16 bf16x8;
typedef __attribute__((ext_vector_type(4))) float f32x4;
typedef __attribute__((ext_vector_type(4))) unsigned short ushort4v;
typedef __attribute__((ext_vector_type(4))) short short4v;

#define NUM_B 2
#define NUM_H 16
#define SEQ   2048
#define EMB   1024
#define LOG2E 1.44269504088896340736f
#define LN10K 13.287712379549449f   // log2(10000)

// ---------------- prep: cast x, transpose+cast weights ----------------
__global__ __launch_bounds__(256) void prep_kernel(
    const float* __restrict__ x, const float* __restrict__ wq,
    const float* __restrict__ wo, bf16_t* __restrict__ xb,
    bf16_t* __restrict__ wqT, bf16_t* __restrict__ woT) {
  __shared__ float tile[32][33];
  int bid = blockIdx.x, tid = threadIdx.x;
  if (bid < 4096) {                 // cast x (4M elems)
    int i = (bid * 256 + tid) * 4;
    f32x4 v = *(const f32x4*)&x[i];
    ushort4v p;
#pragma unroll
    for (int j = 0; j < 4; ++j)
      p[j] = __builtin_bit_cast(unsigned short, __float2bfloat16(v[j]));
    *(ushort4v*)&xb[i] = p;
    return;
  }
  const float* src;
  bf16_t* dst;
  int R, C, c0, r0;
  if (bid < 4096 + 3072) {          // w_qkv [1024,3072] -> wqT [3072,1024]
    int b = bid - 4096;
    src = wq; dst = wqT; R = 1024; C = 3072;
    c0 = (b % 96) * 32; r0 = (b / 96) * 32;
  } else {                          // w_o [1024,1024] -> woT
    int b = bid - 7168;
    src = wo; dst = woT; R = 1024; C = 1024;
    c0 = (b % 32) * 32; r0 = (b / 32) * 32;
  }
  int tx = tid & 31, ty = tid >> 5;
#pragma unroll
  for (int i = 0; i < 4; ++i)
    tile[ty + i * 8][tx] = src[(size_t)(r0 + ty + i * 8) * C + c0 + tx];
  __syncthreads();
#pragma unroll
  for (int i = 0; i < 4; ++i)
    dst[(size_t)(c0 + ty + i * 8) * R + r0 + tx] = __float2bfloat16(tile[tx][ty + i * 8]);
}

// ---------------- GEMM: C = A[M,K]bf16 * Bt[N,K]bf16^T + bias(f32) ----------------
// Tile (32*MT) x 128, BK=32, single-buffer LDS + 2 barriers/iter (r13 proven
// best: 48 us; rope-table epilogue (r15/r16) regressed via VGPR 96 + tail
// load burst -> sincosf epilogue restored). XOR swizzle g^((row>>1)&3) keeps
// b128 frag reads 2-way (free). A-tile=128*MT chunks -> CH=MT/2; B-tile -> 2.
template <int CH>
__device__ __forceinline__ void stage_tile(const bf16_t* __restrict__ G,
                                           int row0, int col0, int ld,
                                           bf16_t* Ls, int tid) {
#pragma unroll
  for (int r = 0; r < CH; ++r) {
    int c = tid + r * 256;
    int row = c >> 2, g = c & 3;
    const char* gp = (const char*)(G + (size_t)(row0 + row) * ld + col0) +
                     ((g ^ ((row >> 1) & 3)) * 16);
    char* lp = (char*)Ls + c * 16;
    __builtin_amdgcn_global_load_lds((const __attribute__((address_space(1))) void*)gp,
                                     (__attribute__((address_space(3))) void*)lp, 16, 0, 0);
  }
}

template <int MODE, int MT>
__global__ __launch_bounds__(256) void gemm_bf16_kernel(
    const bf16_t* __restrict__ A, const bf16_t* __restrict__ Bt,
    const float* __restrict__ bias, bf16_t* __restrict__ out0,
    bf16_t* __restrict__ out1, bf16_t* __restrict__ out2,
    float* __restrict__ outf, int Ndim, int Kdim) {
  __shared__ __align__(16) bf16_t As[MT * 32 * 32];
  __shared__ __align__(16) bf16_t Bs[128 * 32];
  int tid = threadIdx.x;
  int wave = tid >> 6, lane = tid & 63;
  int lr = lane & 15, lq = lane >> 4;
  int m0 = blockIdx.x * (32 * MT), n0 = blockIdx.y * 128;
  int wm = (wave >> 1) * (MT * 16), wn = (wave & 1) * 64;
  int key = (lr >> 1) & 3;            // frag-read swizzle key
  int goff = ((lq ^ key) * 8);        // swizzled 16B-group elem offset
  f32x4 acc[MT][4];
#pragma unroll
  for (int i = 0; i < MT; ++i)
#pragma unroll
    for (int j = 0; j < 4; ++j) acc[i][j] = (f32x4){0.f, 0.f, 0.f, 0.f};

  for (int k0 = 0; k0 < Kdim; k0 += 32) {
    __syncthreads();
    stage_tile<MT / 2>(A, m0, k0, Kdim, As, tid);
    stage_tile<2>(Bt, n0, k0, Kdim, Bs, tid);
    __syncthreads();
    bf16x8 af[MT], bfr[4];
#pragma unroll
    for (int mt = 0; mt < MT; ++mt)
      af[mt] = *(const bf16x8*)&As[(wm + mt * 16 + lr) * 32 + goff];
#pragma unroll
    for (int nt = 0; nt < 4; ++nt)
      bfr[nt] = *(const bf16x8*)&Bs[(wn + nt * 16 + lr) * 32 + goff];
#pragma unroll
    for (int mt = 0; mt < MT; ++mt)
#pragma unroll
      for (int nt = 0; nt < 4; ++nt)
        acc[mt][nt] = __builtin_amdgcn_mfma_f32_16x16x32_bf16(af[mt], bfr[nt], acc[mt][nt], 0, 0, 0);
  }

  if (MODE == 0) {
    // pair (nt=pr, nt=pr+2): same lane holds d=pr*16+lr (<32) and d+32
#pragma unroll
    for (int pr = 0; pr < 2; ++pr) {
      int na = n0 + wn + pr * 16 + lr;
      int nb = na + 32;
      int sec = na >> 10;               // 0=q 1=k 2=v (uniform across pair)
      int h = (na >> 6) & (NUM_H - 1);
      int da = na & 63;                 // < 32
      float bva = bias[na], bvb = bias[nb];
      if (sec == 2) {
#pragma unroll
        for (int mt = 0; mt < MT; ++mt) {
          int mbase = m0 + wm + mt * 16 + lq * 4;
          int b = mbase >> 11;
          int s = mbase & (SEQ - 1);
          int bh = b * NUM_H + h;
          ushort4v pa, pb;
#pragma unroll
          for (int r = 0; r < 4; ++r) {
            pa[r] = __builtin_bit_cast(unsigned short, __float2bfloat16(acc[mt][pr][r] + bva));
            pb[r] = __builtin_bit_cast(unsigned short, __float2bfloat16(acc[mt][pr + 2][r] + bvb));
          }
          *(ushort4v*)&out2[((size_t)bh * 64 + da) * SEQ + s] = pa;
          *(ushort4v*)&out2[((size_t)bh * 64 + da + 32) * SEQ + s] = pb;
        }
      } else {
        bf16_t* dst = (sec == 0) ? out0 : out1;
        float scale = (sec == 0) ? 0.125f : 1.0f;
        int i = da & 31;
        float inv = exp2f(-(float)i * (LN10K / 32.0f));  // 10000^(-i/32)
#pragma unroll
        for (int mt = 0; mt < MT; ++mt) {
          int mbase = m0 + wm + mt * 16 + lq * 4;
          int b = mbase >> 11;
          int s0 = mbase & (SEQ - 1);
          int bh = b * NUM_H + h;
#pragma unroll
          for (int r = 0; r < 4; ++r) {
            float sn, cs;
            sincosf((float)(s0 + r) * inv, &sn, &cs);
            float va = acc[mt][pr][r] + bva;
            float vb = acc[mt][pr + 2][r] + bvb;
            float oa = (va * cs - vb * sn) * scale;
            float ob = (vb * cs + va * sn) * scale;
            size_t rowb = ((size_t)bh * SEQ + (s0 + r)) * 64;
            dst[rowb + da] = __float2bfloat16(oa);
            dst[rowb + da + 32] = __float2bfloat16(ob);
          }
        }
      }
    }
  } else {
#pragma unroll
    for (int nt = 0; nt < 4; ++nt) {
      int n = n0 + wn + nt * 16 + lr;
      float bv = bias[n];
#pragma unroll
      for (int mt = 0; mt < MT; ++mt)
#pragma unroll
        for (int r = 0; r < 4; ++r) {
          int m = m0 + wm + mt * 16 + lq * 4 + r;
          outf[(size_t)m * Ndim + n] = acc[mt][nt][r] + bv;
        }
    }
  }
}

// ---------------- flash attention v8: register-P (no Psh), K=16 PV MFMA ----------------
__device__ __forceinline__ void stage_sw(const char* __restrict__ gbase,
                                         size_t rowStride, bf16_t* lds, int tid) {
  // 64 rows x 128B, swizzled: LDS slot (row,g) <- global (row, g^(row&7))
#pragma unroll
  for (int r = 0; r < 2; ++r) {
    int c = tid + r * 256;
    int row = c >> 3, g = c & 7;
    const char* gp = gbase + (size_t)row * rowStride + ((g ^ (row & 7)) * 16);
    char* lp = (char*)lds + c * 16;
    __builtin_amdgcn_global_load_lds((const __attribute__((address_space(1))) void*)gp,
                                     (__attribute__((address_space(3))) void*)lp, 16, 0, 0);
  }
}

__global__ __launch_bounds__(256) void flash_attn_kernel(
    const bf16_t* __restrict__ Q, const bf16_t* __restrict__ K,
    const bf16_t* __restrict__ Vt, bf16_t* __restrict__ O) {
  __shared__ __align__(16) bf16_t Ks[2][64 * 64];
  __shared__ __align__(16) bf16_t Vs[2][64 * 64];
  int tid = threadIdx.x;
  int wv = tid >> 6, lane = tid & 63;
  int lr = lane & 15, lq = lane >> 4;
  int bx = blockIdx.x;
  int bh = bx & 31;
  int tile = 31 - (bx >> 5);        // longest blocks dispatched first
  int qw0 = tile * 64 + wv * 16;
  const bf16_t* Qb = Q + (size_t)bh * SEQ * 64;
  const bf16_t* Kb = K + (size_t)bh * SEQ * 64;
  const bf16_t* Vb = Vt + (size_t)bh * 64 * SEQ;
  int sw = lr & 7;                  // row-swizzle key for frag reads
  int g0 = (lq ^ sw) * 8;           // elem offset of 16B group lq, row-swizzled
  int g1 = g0 ^ 32;                 // group lq+4

  bf16x8 aq0 = *(const bf16x8*)&Qb[(size_t)(qw0 + lr) * 64 + lq * 8];
  bf16x8 aq1 = *(const bf16x8*)&Qb[(size_t)(qw0 + lr) * 64 + 32 + lq * 8];

  f32x4 Oacc[4];
#pragma unroll
  for (int dt = 0; dt < 4; ++dt) Oacc[dt] = (f32x4){0.f, 0.f, 0.f, 0.f};
  float lrow = 0.f;

  int nch = tile + 1;
  stage_sw((const char*)Kb, 128, Ks[0], tid);
  stage_sw((const char*)Vb, SEQ * 2, Vs[0], tid);

  for (int ch = 0; ch < nch; ++ch) {
    int cur = ch & 1;
    bool diag = (ch == tile);
    __syncthreads();               // buf[cur] staged (vmcnt), buf[1-cur] reads done (lgkm)
    if (ch + 1 < nch) {            // prefetch next chunk; compute below covers latency
      int kvn = (ch + 1) * 64;
      stage_sw((const char*)(Kb + (size_t)kvn * 64), 128, Ks[cur ^ 1], tid);
      stage_sw((const char*)Vb + (size_t)kvn * 2, SEQ * 2, Vs[cur ^ 1], tid);
    }

    // S^T = K*Q^T, p = exp(s) packed in-register (B-frag of K=16 PV MFMA),
    // then O^T += Vt*P, all per kv-sub (independent chains)
#pragma unroll
    for (int sub = 0; sub < 4; ++sub) {
      if (!diag || sub <= wv) {    // wave-uniform
        int rk = (sub * 16 + lr) * 64;
        bf16x8 k0 = *(const bf16x8*)&Ks[cur][rk + g0];
        bf16x8 k1 = *(const bf16x8*)&Ks[cur][rk + g1];
        f32x4 t = (f32x4){0.f, 0.f, 0.f, 0.f};
        t = __builtin_amdgcn_mfma_f32_16x16x32_bf16(k0, aq0, t, 0, 0, 0);
        t = __builtin_amdgcn_mfma_f32_16x16x32_bf16(k1, aq1, t, 0, 0, 0);
        if (diag && sub == wv) {   // causal: kv_local > q_local
#pragma unroll
          for (int r = 0; r < 4; ++r)
            if (lq * 4 + r > lr) t[r] = -1e30f;
        }
        short4v pp;
#pragma unroll
        for (int r = 0; r < 4; ++r) {
          float p = exp2f(t[r] * LOG2E);
          lrow += p;
          pp[r] = __builtin_bit_cast(short, __float2bfloat16(p));
        }
        // PV: A = Vt[d-sub][kv 16 of this sub] (b64, swizzled), B = pp (regs)
#pragma unroll
        for (int dt = 0; dt < 4; ++dt) {
          int row = dt * 16 + lr;
          int grp = (sub * 2 + (lq >> 1)) ^ sw;         // 16B group, swizzled
          short4v av = *(const short4v*)&Vs[cur][row * 64 + grp * 8 + (lq & 1) * 4];
          Oacc[dt] = __builtin_amdgcn_mfma_f32_16x16x16bf16_1k(av, pp, Oacc[dt], 0, 0, 0);
        }
      }
    }
  }

  lrow += __shfl_xor(lrow, 16, 64);
  lrow += __shfl_xor(lrow, 32, 64);

  int b = bh >> 4, h = bh & (NUM_H - 1);
  int q = qw0 + lr;
  size_t base = (((size_t)b * SEQ + q) * NUM_H + h) * 64;
  float rinv = 1.0f / lrow;
#pragma unroll
  for (int dt = 0; dt < 4; ++dt) {
    ushort4v ok;
#pragma unroll
    for (int r = 0; r < 4; ++r)
      ok[r] = __builtin_bit_cast(unsigned short, __float2bfloat16(Oacc[dt][r] * rinv));
    *(ushort4v*)&O[base + dt * 16 + lq * 4] = ok;
  }
}

extern "C" void kernel_launch(void* const* d_in, const int* in_sizes, int n_in,
                              void* d_out, int out_size, void* d_ws, size_t ws_size,
                              hipStream_t stream) {
  const float* x      = (const float*)d_in[0];
  const float* w_qkv  = (const float*)d_in[1];
  const float* b_qkv  = (const float*)d_in[2];
  const float* w_o    = (const float*)d_in[3];
  const float* b_o    = (const float*)d_in[4];
  float* out = (float*)d_out;

  bf16_t* ws    = (bf16_t*)d_ws;
  bf16_t* xb    = ws;                       // [4096,1024]   8MB
  bf16_t* wqkvT = xb + 4 * 1024 * 1024;     // [3072,1024]   6MB
  bf16_t* woT   = wqkvT + 3072 * 1024;      // [1024,1024]   2MB
  bf16_t* Qb    = woT + 1024 * 1024;        // [32,2048,64]  8MB
  bf16_t* Kb    = Qb + 4 * 1024 * 1024;     // [32,2048,64]  8MB
  bf16_t* Vt    = Kb + 4 * 1024 * 1024;     // [32,64,2048]  8MB
  bf16_t* attn  = Vt + 4 * 1024 * 1024;     // [4096,1024]   8MB  (48MB total)

  prep_kernel<<<8192, 256, 0, stream>>>(x, w_qkv, w_o, xb, wqkvT, woT);
  gemm_bf16_kernel<0, 4><<<dim3(32, 24), 256, 0, stream>>>(
      xb, wqkvT, b_qkv, Qb, Kb, Vt, nullptr, 3072, 1024);
  flash_attn_kernel<<<1024, 256, 0, stream>>>(Qb, Kb, Vt, attn);
  gemm_bf16_kernel<1, 2><<<dim3(64, 8), 256, 0, stream>>>(
      attn, woT, b_o, nullptr, nullptr, nullptr, out, 1024, 1024);
}